// Round 1
// baseline (173.187 us; speedup 1.0000x reference)
//
#include <hip/hip_runtime.h>

#define N_PTS 1000000
#define H_DIM 200
#define W_DIM 70400
#define FILL_V -9999999.0f

typedef float v2f __attribute__((ext_vector_type(2)));

__device__ __forceinline__ v2f fma2(v2f a, v2f b, v2f c) {
    return __builtin_elementwise_fma(a, b, c);   // -> v_pk_fma_f32 on gfx950
}

// ---------------------------------------------------------------------------
// Kernel A: per-point MLP (4->18->36->36->1), ONE point per thread.
// UNCHANGED from the 172.6us version (control for this round's colmax fix).
// Weights read wave-uniform from global (scalarized to s_load by compiler;
// R9 counters: LDS=0, SGPR=112, no scratch). Dot products PACKED over k as
// float2 -> v_pk_fma_f32 (2 FMA/instr). Layer 4 fused into layer 3.
// History: LDS-staged weights = 117us; scalar 1-pt = 104us; 2-pt = spill.
// List entry: .x = value bits, .y = (point_index << 8) | row  (row<200<256).
// Last-write-wins scatter: point survives iff no LATER point hit (row,col).
// ---------------------------------------------------------------------------
__global__ void __launch_bounds__(256) mlp_scatter_kernel(
    const float* __restrict__ input,        // [4][N]
    const int* __restrict__ tindex,         // [N][2] int32 (row, col)
    const float* __restrict__ w1, const float* __restrict__ b1,
    const float* __restrict__ w2, const float* __restrict__ b2,
    const float* __restrict__ w3, const float* __restrict__ b3,
    const float* __restrict__ w4, const float* __restrict__ b4,
    int* __restrict__ counts,               // [W]
    uint2* __restrict__ list,               // [W][maxk]
    int maxk)
{
    // empty-branch (reference: tensor_index[0,0] == -1 -> no scatter)
    if (tindex[0] == -1) return;

    const int i = blockIdx.x * 256 + threadIdx.x;
    if (i >= N_PTS) return;

    const v2f* __restrict__ w1v = (const v2f*)w1;   // rows of 4 = 2 v2f
    const v2f* __restrict__ w2v = (const v2f*)w2;   // rows of 18 = 9 v2f
    const v2f* __restrict__ w3v = (const v2f*)w3;   // rows of 36 = 18 v2f

    const v2f x01 = { input[0 * N_PTS + i], input[1 * N_PTS + i] };
    const v2f x23 = { input[2 * N_PTS + i], input[3 * N_PTS + i] };

    // layer 1: 18 outputs, k packed (4 -> 2 pairs)
    v2f h1v[9];
#pragma unroll
    for (int o = 0; o < 18; ++o) {
        v2f acc = { b1[o], 0.0f };               // bias rides in .x
        acc = fma2(w1v[o * 2 + 0], x01, acc);
        acc = fma2(w1v[o * 2 + 1], x23, acc);
        const float h = fmaxf(acc.x + acc.y, 0.0f);
        if (o & 1) h1v[o >> 1].y = h; else h1v[o >> 1].x = h;
    }

    // layer 2: 36 outputs, k packed (18 -> 9 pairs)
    v2f h2v[18];
#pragma unroll
    for (int o = 0; o < 36; ++o) {
        v2f acc = { b2[o], 0.0f };
#pragma unroll
        for (int q = 0; q < 9; ++q)
            acc = fma2(w2v[o * 9 + q], h1v[q], acc);
        const float h = fmaxf(acc.x + acc.y, 0.0f);
        if (o & 1) h2v[o >> 1].y = h; else h2v[o >> 1].x = h;
    }

    // layer 3 (k packed, 36 -> 18 pairs) with layer 4 fused
    float v = b4[0];
#pragma unroll
    for (int o = 0; o < 36; ++o) {
        v2f acc = { b3[o], 0.0f };
#pragma unroll
        for (int q = 0; q < 18; ++q)
            acc = fma2(w3v[o * 18 + q], h2v[q], acc);
        v = fmaf(w4[o], fmaxf(acc.x + acc.y, 0.0f), v);
    }

    const int2 hw = ((const int2*)tindex)[i];   // (row, col)
    const int pos = atomicAdd(&counts[hw.y], 1);
    if (pos < maxk) {   // never overflows statistically at maxk>=64 (mean 14.2/col)
        uint2 e;
        e.x = __float_as_uint(v);
        e.y = ((unsigned)i << 8) | (unsigned)hw.x;
        list[(size_t)hw.y * maxk + pos] = e;
    }
}

// Wave-local LDS ordering: all 64 lanes' ds ops from prior instructions are
// drained. "memory" clobber stops the compiler moving the following ds_read
// above this point (mem-op vs mem-op ordering, which the clobber DOES cover;
// the rule-#18 hazard only applies to register-only consumers).
__device__ __forceinline__ void lds_wave_fence() {
    asm volatile("s_waitcnt lgkmcnt(0)" ::: "memory");
}

// ---------------------------------------------------------------------------
// Kernel B v2: grid-stride, BARRIER-FREE column max.
// R0 theory: old version (17600 blocks, 2 full-block __syncthreads each, LDS
// table re-init per block) was overhead/latency-bound at ~70-80us for ~13 MB
// of traffic. The winner table rowwin[y] is per-WAVE private, so cross-wave
// barriers were never needed: within one wave the ds_max_u64 for all 64
// lanes retires as one in-order DS instruction; lgkmcnt(0) suffices before
// the read-back.
// New shape: 2200 blocks x 4 waves, each wave owns 8 columns sequentially
// (2200*4*8 == 70400). LDS table zeroed ONCE per wave; after each column,
// only the <=c dirtied rows are re-zeroed. Dedup semantics identical:
// atomicMax key = ((i<<8|row) << 32) | value_bits -> highest point index
// wins per row; lane reads its row's winner value; wave max-reduce.
// Predicted: ~8-15us (was ~75), total ~100-112us.
// ---------------------------------------------------------------------------
__global__ void __launch_bounds__(256) colmax_kernel(
    const int* __restrict__ tindex,
    const int* __restrict__ counts,
    const uint2* __restrict__ list,
    float* __restrict__ out,
    int maxk)
{
    __shared__ unsigned long long rowwin[4][200];
    const int lane = threadIdx.x;        // 0..63
    const int y    = threadIdx.y;        // 0..3
    unsigned long long* tbl = rowwin[y];

    const bool empty = (tindex[0] == -1);

    if (blockIdx.x == 0 && lane == 0 && y == 0)
        out[W_DIM] = empty ? 0.0f : 1.0f;    // flag output

    // zero the full per-wave table once
    tbl[lane]       = 0ull;
    tbl[lane + 64]  = 0ull;
    tbl[lane + 128] = 0ull;
    if (lane < 8) tbl[lane + 192] = 0ull;
    lds_wave_fence();

    const int step = gridDim.x * 4;
    for (int w = blockIdx.x * 4 + y; w < W_DIM; w += step) {
        int c = 0;
        if (!empty) {
            c = counts[w];
            if (c > maxk) c = maxk;
        }

        uint2 e = make_uint2(0u, 0u);
        const bool have = (lane < c);
        float v = FILL_V;
        if (have) {
            e = list[(size_t)w * maxk + lane];
            const unsigned long long key64 =
                ((unsigned long long)e.y << 32) | (unsigned long long)e.x;
            atomicMax(&tbl[e.y & 0xFFu], key64);
        }
        lds_wave_fence();                 // ds_max drained -> winners final
        if (have) {
            const unsigned long long winner = tbl[e.y & 0xFFu];
            v = __uint_as_float((unsigned)(winner & 0xFFFFFFFFull));
            tbl[e.y & 0xFFu] = 0ull;      // re-zero only dirtied rows
        }
        lds_wave_fence();                 // zeros land before next column

#pragma unroll
        for (int off = 32; off > 0; off >>= 1)
            v = fmaxf(v, __shfl_down(v, off, 64));

        if (lane == 0) out[w] = v;
    }
}

extern "C" void kernel_launch(void* const* d_in, const int* in_sizes, int n_in,
                              void* d_out, int out_size, void* d_ws, size_t ws_size,
                              hipStream_t stream) {
    const float* input  = (const float*)d_in[0];
    const int*   tindex = (const int*)d_in[1];   // int32 on device
    const float* w1 = (const float*)d_in[2];
    const float* b1 = (const float*)d_in[3];
    const float* w2 = (const float*)d_in[4];
    const float* b2 = (const float*)d_in[5];
    const float* w3 = (const float*)d_in[6];
    const float* b3 = (const float*)d_in[7];
    const float* w4 = (const float*)d_in[8];
    const float* b4 = (const float*)d_in[9];
    float* out = (float*)d_out;

    // workspace: counts [70400 int] | list [70400][maxk] uint2
    int*   counts = (int*)d_ws;
    uint2* list   = (uint2*)((char*)d_ws + (size_t)W_DIM * sizeof(int));

    size_t avail = (ws_size > (size_t)W_DIM * sizeof(int))
                       ? ws_size - (size_t)W_DIM * sizeof(int) : 0;
    int maxk = (int)(avail / ((size_t)W_DIM * sizeof(uint2)));
    if (maxk > 64) maxk = 64;
    if (maxk < 1)  maxk = 1;

    hipMemsetAsync(counts, 0, (size_t)W_DIM * sizeof(int), stream);

    mlp_scatter_kernel<<<(N_PTS + 255) / 256, 256, 0, stream>>>(
        input, tindex, w1, b1, w2, b2, w3, b3, w4, b4, counts, list, maxk);

    // grid-stride: 2200 blocks x 4 waves x 8 columns = 70400 exactly
    colmax_kernel<<<2200, dim3(64, 4), 0, stream>>>(
        tindex, counts, list, out, maxk);
}